// Round 3
// baseline (291.973 us; speedup 1.0000x reference)
//
#include <hip/hip_runtime.h>
#include <hip/hip_bf16.h>
#include <stdint.h>

#define N_LGN   17400
#define N_POST  50000
#define NNZ     800000
#define N_BASIS 5
#define ELL_CAP 48

// ---------------- transpose x (128 x 17400) fp32 -> xTb (17400 x 64) bf16x2 ----------------
// also zeroes counts[] (runs before scatter in stream order)
__global__ __launch_bounds__(256) void k_transpose_bf16(const float* __restrict__ inp,
                                                        __hip_bfloat162* __restrict__ xTb,
                                                        int* __restrict__ counts) {
    __shared__ float tile[64 * 129];
    int tid = threadIdx.x;
    int gid = blockIdx.x * 256 + tid;
    if (gid < N_POST) counts[gid] = 0;      // 272*256 = 69632 >= 50000
    int c0 = blockIdx.x * 64;
    for (int it = 0; it < 32; ++it) {
        int flat = it * 256 + tid;
        int s  = flat >> 6;
        int cl = flat & 63;
        int c  = c0 + cl;
        float v = 0.0f;
        if (c < N_LGN) v = inp[s * N_LGN + c];
        tile[cl * 129 + s] = v;
    }
    __syncthreads();
    for (int it = 0; it < 16; ++it) {
        int flat = it * 256 + tid;
        int cl = flat >> 6;
        int sp = flat & 63;
        int c  = c0 + cl;
        if (c < N_LGN) {
            float2 f = make_float2(tile[cl * 129 + 2 * sp], tile[cl * 129 + 2 * sp + 1]);
            xTb[c * 64 + sp] = __float22bfloat162_rn(f);
        }
    }
}

// ---------------- pack helpers ----------------
__device__ inline unsigned pack_bf2(float a, float b) {
    __hip_bfloat162 h = __float22bfloat162_rn(make_float2(a, b));
    union { __hip_bfloat162 h; unsigned u; } cvt;
    cvt.h = h;
    return cvt.u;                            // low16 = a, high16 = b
}
__device__ inline unsigned pack_bf1(float a) {
    union { __hip_bfloat16 h; unsigned short u; } cvt;
    cvt.h = __float2bfloat16(a);
    return (unsigned)cvt.u;                  // low16 = a
}

// ---------------- ELL scatter with precomputed per-edge factors (16B records) ----------------
// record: {col*256 (byte offset), bf16 f0|f1, bf16 f2|f3, bf16 f4}
__global__ __launch_bounds__(256) void k_scatter16(const int4* __restrict__ idx2,
                                                   const float2* __restrict__ w2,
                                                   const int2* __restrict__ syn2,
                                                   const float* __restrict__ sw,
                                                   int* __restrict__ counts,
                                                   int4* __restrict__ ell) {
    int t = blockIdx.x * 256 + threadIdx.x;
    if (t >= NNZ / 2) return;
    int4 rc = idx2[t];
    float2 ww = w2[t];
    int2 sy = syn2[t];
    {
        const float* f = sw + sy.x * N_BASIS;
        float w = ww.x;
        int r = atomicAdd(&counts[rc.x], 1);
        if (r < ELL_CAP)
            ell[rc.x * ELL_CAP + r] = make_int4(rc.y << 8,
                                                (int)pack_bf2(w * f[0], w * f[1]),
                                                (int)pack_bf2(w * f[2], w * f[3]),
                                                (int)pack_bf1(w * f[4]));
    }
    {
        const float* f = sw + sy.y * N_BASIS;
        float w = ww.y;
        int r = atomicAdd(&counts[rc.z], 1);
        if (r < ELL_CAP)
            ell[rc.z * ELL_CAP + r] = make_int4(rc.w << 8,
                                                (int)pack_bf2(w * f[0], w * f[1]),
                                                (int)pack_bf2(w * f[2], w * f[3]),
                                                (int)pack_bf1(w * f[4]));
    }
}

// ---------------- main compute: 2 rows per wave, 4 waves per block (8 rows/block) ----------------
__device__ __forceinline__ void edge_fma(const int4& e, const char* xb,
                                         float (&a0)[N_BASIS], float (&a1)[N_BASIS]) {
    float2 xv = __bfloat1622float2(*(const __hip_bfloat162*)(xb + e.x));
    float f0 = __int_as_float(e.y << 16);
    float f1 = __int_as_float(e.y & 0xffff0000);
    float f2 = __int_as_float(e.z << 16);
    float f3 = __int_as_float(e.z & 0xffff0000);
    float f4 = __int_as_float(e.w << 16);
    a0[0] = fmaf(xv.x, f0, a0[0]); a1[0] = fmaf(xv.y, f0, a1[0]);
    a0[1] = fmaf(xv.x, f1, a0[1]); a1[1] = fmaf(xv.y, f1, a1[1]);
    a0[2] = fmaf(xv.x, f2, a0[2]); a1[2] = fmaf(xv.y, f2, a1[2]);
    a0[3] = fmaf(xv.x, f3, a0[3]); a1[3] = fmaf(xv.y, f3, a1[3]);
    a0[4] = fmaf(xv.x, f4, a0[4]); a1[4] = fmaf(xv.y, f4, a1[4]);
}

__global__ __launch_bounds__(256, 6) void k_compute2(const __hip_bfloat162* __restrict__ xTb,
                                                     const int4* __restrict__ ell,
                                                     const int* __restrict__ counts,
                                                     float2* __restrict__ out2) {
    __shared__ float accLds[40 * 133];      // [j = rl*5+r][s], pitch 133 (2-way max conflicts)
    int tid  = threadIdx.x;
    int wave = tid >> 6;
    int lane = tid & 63;
    int nA = blockIdx.x * 8 + wave * 2;     // 6250 blocks * 8 rows
    int nB = nA + 1;
    int cA = min(counts[nA], ELL_CAP);
    int cB = min(counts[nB], ELL_CAP);
    const int4* eA = ell + (size_t)nA * ELL_CAP;
    const int4* eB = ell + (size_t)nB * ELL_CAP;
    const char* xb = (const char*)xTb + lane * 4;

    float aA0[N_BASIS] = {0,0,0,0,0}, aA1[N_BASIS] = {0,0,0,0,0};
    float aB0[N_BASIS] = {0,0,0,0,0}, aB1[N_BASIS] = {0,0,0,0,0};

    int m = min(cA, cB);
    int j = 0;
    for (; j < m; ++j) {                    // two independent chains in flight
        int4 e0 = eA[j];
        int4 e1 = eB[j];
        edge_fma(e0, xb, aA0, aA1);
        edge_fma(e1, xb, aB0, aB1);
    }
    for (; j < cA; ++j) { int4 e = eA[j]; edge_fma(e, xb, aA0, aA1); }
    for (; j < cB; ++j) { int4 e = eB[j]; edge_fma(e, xb, aB0, aB1); }

#pragma unroll
    for (int r = 0; r < N_BASIS; ++r) {
        int jjA = (wave * 2) * 5 + r;
        int jjB = (wave * 2 + 1) * 5 + r;
        accLds[jjA * 133 + 2 * lane]     = aA0[r];
        accLds[jjA * 133 + 2 * lane + 1] = aA1[r];
        accLds[jjB * 133 + 2 * lane]     = aB0[r];
        accLds[jjB * 133 + 2 * lane + 1] = aB1[r];
    }
    __syncthreads();

    // epilogue: 128 s x 40 floats = 2560 float2; contiguous 160B runs per s
    int base2 = blockIdx.x * 20;
    for (int it = 0; it < 10; ++it) {
        int flat = it * 256 + tid;          // 0..2559
        int s  = flat / 20;
        int jj = flat % 20;
        float f0 = accLds[(2 * jj) * 133 + s];
        float f1 = accLds[(2 * jj + 1) * 133 + s];
        out2[s * 125000 + base2 + jj] = make_float2(f0, f1);
    }
}

// ================= fallback path (8B records, proven in round 2) =================
__global__ __launch_bounds__(256) void k_scatter_ell8(const int4* __restrict__ idx2,
                                                      const float2* __restrict__ w2,
                                                      const int2* __restrict__ syn2,
                                                      int* __restrict__ counts,
                                                      int2* __restrict__ ell) {
    int t = blockIdx.x * 256 + threadIdx.x;
    if (t >= NNZ / 2) return;
    int4 rc = idx2[t];
    float2 ww = w2[t];
    int2 sy = syn2[t];
    int r0 = atomicAdd(&counts[rc.x], 1);
    if (r0 < ELL_CAP) ell[rc.x * ELL_CAP + r0] = make_int2(rc.y | (sy.x << 16), __float_as_int(ww.x));
    int r1 = atomicAdd(&counts[rc.z], 1);
    if (r1 < ELL_CAP) ell[rc.z * ELL_CAP + r1] = make_int2(rc.w | (sy.y << 16), __float_as_int(ww.y));
}

__global__ __launch_bounds__(512, 8) void k_compute8(const __hip_bfloat162* __restrict__ xTb,
                                                     const int2* __restrict__ edges,
                                                     const int* __restrict__ counts,
                                                     const float* __restrict__ sw,
                                                     float2* __restrict__ out2) {
    __shared__ float facs[64];
    __shared__ float accLds[40 * 132];
    int tid  = threadIdx.x;
    if (tid < 50) facs[tid] = sw[tid];
    int wave = tid >> 6;
    int lane = tid & 63;
    int n     = blockIdx.x * 8 + wave;
    int start = n * ELL_CAP;
    int cnt   = min(counts[n], ELL_CAP);
    __syncthreads();

    float a0[N_BASIS] = {0,0,0,0,0};
    float a1[N_BASIS] = {0,0,0,0,0};
    const int2* ep = edges + start;
    for (int j = 0; j < cnt; ++j) {
        int2 e0 = ep[j];
        int c0 = e0.x & 0xFFFF, sy0 = e0.x >> 16;
        float2 x0 = __bfloat1622float2(xTb[c0 * 64 + lane]);
        float w0 = __int_as_float(e0.y);
#pragma unroll
        for (int r = 0; r < N_BASIS; ++r) {
            float f0 = w0 * facs[sy0 * 5 + r];
            a0[r] = fmaf(x0.x, f0, a0[r]);
            a1[r] = fmaf(x0.y, f0, a1[r]);
        }
    }
#pragma unroll
    for (int r = 0; r < N_BASIS; ++r) {
        int jj = wave * 5 + r;
        accLds[jj * 132 + 2 * lane]     = a0[r];
        accLds[jj * 132 + 2 * lane + 1] = a1[r];
    }
    __syncthreads();
    int base2 = blockIdx.x * 20;
    for (int it = 0; it < 5; ++it) {
        int flat = it * 512 + tid;
        int s  = flat / 20;
        int jj = flat % 20;
        float f0 = accLds[(2 * jj) * 132 + s];
        float f1 = accLds[(2 * jj + 1) * 132 + s];
        out2[s * 125000 + base2 + jj] = make_float2(f0, f1);
    }
}

// ---------------- launcher ----------------
extern "C" void kernel_launch(void* const* d_in, const int* in_sizes, int n_in,
                              void* d_out, int out_size, void* d_ws, size_t ws_size,
                              hipStream_t stream) {
    const float* inp     = (const float*)d_in[0];   // (1,128,17400) fp32
    const int*   indices = (const int*)d_in[1];     // (800000,2)
    const float* weights = (const float*)d_in[2];   // (800000,)
    const float* sw      = (const float*)d_in[3];   // (10,5)
    const int*   syn     = (const int*)d_in[4];     // (800000,)

    char* ws = (char*)d_ws;
    __hip_bfloat162* xTb = (__hip_bfloat162*)(ws);          // 4,454,400 B
    int* counts          = (int*)(ws + 4454400);            // 200,000 B
    char* ellBase        = ws + 4654400;

    const size_t NEED16 = 4654400ULL + (size_t)N_POST * ELL_CAP * 16;  // 43,054,400
    const size_t NEED8  = 4654400ULL + (size_t)N_POST * ELL_CAP * 8;   // 23,854,400

    k_transpose_bf16<<<(N_LGN + 63) / 64, 256, 0, stream>>>(inp, xTb, counts);

    if (ws_size >= NEED16) {
        int4* ell = (int4*)ellBase;
        k_scatter16<<<(NNZ / 2 + 255) / 256, 256, 0, stream>>>(
            (const int4*)indices, (const float2*)weights, (const int2*)syn, sw, counts, ell);
        k_compute2<<<N_POST / 8, 256, 0, stream>>>(xTb, ell, counts, (float2*)d_out);
    } else if (ws_size >= NEED8) {
        int2* ell = (int2*)ellBase;
        k_scatter_ell8<<<(NNZ / 2 + 255) / 256, 256, 0, stream>>>(
            (const int4*)indices, (const float2*)weights, (const int2*)syn, counts, ell);
        k_compute8<<<N_POST / 8, 512, 0, stream>>>(xTb, ell, counts, sw, (float2*)d_out);
    }
}